// Round 1
// baseline (3456.269 us; speedup 1.0000x reference)
//
#include <hip/hip_runtime.h>
#include <hip/hip_bf16.h>

typedef _Float16 half2v __attribute__((ext_vector_type(2)));
typedef _Float16 half4v __attribute__((ext_vector_type(4)));
typedef _Float16 half8v __attribute__((ext_vector_type(8)));
typedef float f32x4 __attribute__((ext_vector_type(4)));

#define T_STEPS 256
#define BATCH 64
#define NHID 512
#define NINP 512
#define MROWS (T_STEPS * BATCH)          // 16384
#define KDIM (2 * NINP)                  // 1024
#define NOUT (2 * NHID + NHID)           // 1536

// ---------------------------------------------------------------- converts

__global__ __launch_bounds__(256) void k_convert_x(
    const float* __restrict__ inp, const float* __restrict__ sem,
    _Float16* __restrict__ xh) {
  int idx = blockIdx.x * 256 + threadIdx.x;
  const int G = MROWS * KDIM / 4;        // 4,194,304 groups of 4
  for (int g = idx; g < G; g += 2048 * 256) {
    int e = g * 4;
    int m = e >> 10, k = e & 1023;
    const float* src = (k < NINP) ? (inp + (size_t)m * NINP + k)
                                  : (sem + (size_t)m * NINP + (k - NINP));
    float4 v = *(const float4*)src;
    half4v o = { (_Float16)v.x, (_Float16)v.y, (_Float16)v.z, (_Float16)v.w };
    *(half4v*)(xh + (size_t)e) = o;
  }
}

__global__ __launch_bounds__(256) void k_convert_w(
    const float* __restrict__ W_ioux, const float* __restrict__ W_fx,
    const float* __restrict__ b_ioux, const float* __restrict__ b_fx,
    _Float16* __restrict__ wbig, float* __restrict__ biasN) {
  int g = blockIdx.x * 256 + threadIdx.x;   // exactly NOUT*KDIM/4 = 393216
  int e = g * 4;
  int n = e >> 10, k = e & 1023;
  const float* src = (n < 2 * NHID) ? (W_ioux + (size_t)n * KDIM + k)
                                    : (W_fx + (size_t)(n - 2 * NHID) * KDIM + k);
  float4 v = *(const float4*)src;
  half4v o = { (_Float16)v.x, (_Float16)v.y, (_Float16)v.z, (_Float16)v.w };
  *(half4v*)(wbig + (size_t)e) = o;
  if (g < NOUT) biasN[g] = (g < 2 * NHID) ? b_ioux[g] : b_fx[g - 2 * NHID];
}

__global__ __launch_bounds__(256) void k_convert_wrec(
    const float* __restrict__ W_iouh, const float* __restrict__ W_Uh,
    _Float16* __restrict__ wrec) {
  int g = blockIdx.x * 256 + threadIdx.x;   // exactly 786432/4 = 196608
  int e = g * 4;
  const int NI = 2 * NHID * NHID;           // 524288
  const float* src = (e < NI) ? (W_iouh + e) : (W_Uh + (e - NI));
  float4 v = *(const float4*)src;
  half4v o = { (_Float16)v.x, (_Float16)v.y, (_Float16)v.z, (_Float16)v.w };
  *(half4v*)(wrec + (size_t)e) = o;
}

// ---------------------------------------------------------------- GEMM
// C[m][n] = sum_k A[m][k]*B[n][k] + biasN[n]; A=[M][K] f16, B=[N][K] f16, C f32.
// m97 structure: 128x128 tile, BK=32, 256 threads (4 waves, 2x2), global_load_lds.

__device__ __forceinline__ void gload16(const void* g, void* l) {
  __builtin_amdgcn_global_load_lds(
      (const __attribute__((address_space(1))) unsigned int*)g,
      (__attribute__((address_space(3))) unsigned int*)l, 16, 0, 0);
}

__global__ __launch_bounds__(256) void gemm_bt(
    const _Float16* __restrict__ A, const _Float16* __restrict__ Bm,
    const float* __restrict__ biasN, float* __restrict__ C,
    int M, int N, int K) {
  __shared__ __align__(16) _Float16 As[128 * 32];
  __shared__ __align__(16) _Float16 Bs[128 * 32];
  const int tid = threadIdx.x;
  const int lane = tid & 63;
  const int w = tid >> 6;
  const int wr = w >> 1, wc = w & 1;
  const int nbm = M >> 7;
  const int bm = blockIdx.x % nbm, bn = blockIdx.x / nbm;
  const int m0 = bm << 7, n0 = bn << 7;
  const int lr = lane & 15, lh = lane >> 4;

  f32x4 acc[4][4] = {};

  for (int kk = 0; kk < K; kk += 32) {
#pragma unroll
    for (int c = 0; c < 2; ++c) {
      int L = (c * 256 + tid) * 16;  // byte offset within 8KB tile
      int row = L >> 6, inrow = L & 63;
      gload16((const char*)A + ((size_t)(m0 + row) * K + kk) * 2 + inrow,
              (char*)As + L);
      gload16((const char*)Bm + ((size_t)(n0 + row) * K + kk) * 2 + inrow,
              (char*)Bs + L);
    }
    __syncthreads();
    half8v af[4], bf[4];
#pragma unroll
    for (int i = 0; i < 4; ++i)
      af[i] = *(const half8v*)&As[(wr * 64 + i * 16 + lr) * 32 + lh * 8];
#pragma unroll
    for (int i = 0; i < 4; ++i)
      bf[i] = *(const half8v*)&Bs[(wc * 64 + i * 16 + lr) * 32 + lh * 8];
#pragma unroll
    for (int i = 0; i < 4; ++i)
#pragma unroll
      for (int j = 0; j < 4; ++j)
        acc[i][j] = __builtin_amdgcn_mfma_f32_16x16x32_f16(af[i], bf[j], acc[i][j], 0, 0, 0);
    __syncthreads();
  }

#pragma unroll
  for (int i = 0; i < 4; ++i)
#pragma unroll
    for (int j = 0; j < 4; ++j) {
      int n = n0 + wc * 64 + j * 16 + lr;
      float bv = biasN[n];
#pragma unroll
      for (int q = 0; q < 4; ++q) {
        int m = m0 + wr * 64 + i * 16 + lh * 4 + q;
        C[(size_t)m * N + n] = acc[i][j][q] + bv;
      }
    }
}

// ---------------------------------------------------------------- recurrence
// One workgroup (1024 threads, 16 waves) per batch chain. No cross-WG sync.

__device__ __forceinline__ float dot8(half8v a, half8v b, float acc) {
  acc = __builtin_amdgcn_fdot2(__builtin_shufflevector(a, a, 0, 1),
                               __builtin_shufflevector(b, b, 0, 1), acc, false);
  acc = __builtin_amdgcn_fdot2(__builtin_shufflevector(a, a, 2, 3),
                               __builtin_shufflevector(b, b, 2, 3), acc, false);
  acc = __builtin_amdgcn_fdot2(__builtin_shufflevector(a, a, 4, 5),
                               __builtin_shufflevector(b, b, 4, 5), acc, false);
  acc = __builtin_amdgcn_fdot2(__builtin_shufflevector(a, a, 6, 7),
                               __builtin_shufflevector(b, b, 6, 7), acc, false);
  return acc;
}

__global__ __launch_bounds__(1024) void recur(
    const _Float16* __restrict__ Wrec,   // [1024][512] W_iouh, then [512][512] W_Uh
    const float* __restrict__ b_iouh, const float* __restrict__ b_Uh,
    const float* __restrict__ hx, const float* __restrict__ proj,
    float* __restrict__ out) {
  __shared__ float hf[NHID];
  __shared__ float zb[NHID];
  __shared__ float prow[NOUT];
  __shared__ float biou[2 * NHID];
  __shared__ float bUhs[NHID];
  __shared__ __align__(16) _Float16 hh[NHID];
  __shared__ __align__(16) _Float16 rh[NHID];

  const int b = blockIdx.x;
  const int tid = threadIdx.x;
  const int lane = tid & 63, w = tid >> 6;
  const int oct = lane >> 3, okt = lane & 7;

  if (tid < NHID) {
    float h0 = hx[(size_t)b * NHID + tid];
    hf[tid] = h0;
    hh[tid] = (_Float16)h0;
    bUhs[tid] = b_Uh[tid];
  }
  biou[tid] = b_iouh[tid];  // tid covers 0..1023 exactly
  __syncthreads();

  const _Float16* WU = Wrec + (size_t)2 * NHID * NHID;

  for (int t = 0; t < T_STEPS; ++t) {
    {
      const float* p = proj + (size_t)(t * BATCH + b) * NOUT;
      prow[tid] = p[tid];
      if (tid < NOUT - 1024) prow[tid + 1024] = p[tid + 1024];
    }
    __syncthreads();

    // mv1: iou[j] = prow[j] + biou[j] + W_iouh[j,:] . h   (j = 0..1023)
#pragma unroll 2
    for (int p = 0; p < 8; ++p) {
      int j = p * 128 + w * 8 + oct;
      const _Float16* wp = Wrec + (size_t)j * NHID + okt * 8;
      float acc = 0.f;
#pragma unroll
      for (int it = 0; it < 8; ++it) {
        half8v wv = *(const half8v*)(wp + it * 64);
        half8v hv = *(const half8v*)(&hh[it * 64 + okt * 8]);
        acc = dot8(wv, hv, acc);
      }
      acc += __shfl_xor(acc, 1);
      acc += __shfl_xor(acc, 2);
      acc += __shfl_xor(acc, 4);
      if (okt == 0) {
        float v = acc + prow[j] + biou[j];
        float s = 1.f / (1.f + __expf(-v));
        if (j < NHID) zb[j] = s;
        else rh[j - NHID] = (_Float16)(s * hf[j - NHID]);
      }
    }
    __syncthreads();

    // mv2: htilde_pre[i] = prow[1024+i] + bUh[i] + W_Uh[i,:] . (r*h)
#pragma unroll 2
    for (int p = 0; p < 4; ++p) {
      int i = p * 128 + w * 8 + oct;
      const _Float16* wp = WU + (size_t)i * NHID + okt * 8;
      float acc = 0.f;
#pragma unroll
      for (int it = 0; it < 8; ++it) {
        half8v wv = *(const half8v*)(wp + it * 64);
        half8v rv = *(const half8v*)(&rh[it * 64 + okt * 8]);
        acc = dot8(wv, rv, acc);
      }
      acc += __shfl_xor(acc, 1);
      acc += __shfl_xor(acc, 2);
      acc += __shfl_xor(acc, 4);
      if (okt == 0) {
        float v = acc + prow[1024 + i] + bUhs[i];
        float e = __expf(-2.f * fabsf(v));
        float th = (1.f - e) / (1.f + e);
        th = (v < 0.f) ? -th : th;
        float z = zb[i];
        float hn = fmaf(z, th - hf[i], hf[i]);
        out[(size_t)(t * BATCH + b) * NHID + i] = hn;
        hf[i] = hn;
        hh[i] = (_Float16)hn;
      }
    }
    __syncthreads();
  }

  if (tid < NHID)
    out[(size_t)T_STEPS * BATCH * NHID + (size_t)b * NHID + tid] = hf[tid];
}

// ---------------------------------------------------------------- launcher

extern "C" void kernel_launch(void* const* d_in, const int* in_sizes, int n_in,
                              void* d_out, int out_size, void* d_ws, size_t ws_size,
                              hipStream_t stream) {
  const float* inputs = (const float*)d_in[0];
  const float* sememe = (const float*)d_in[1];
  const float* hx     = (const float*)d_in[2];
  const float* W_ioux = (const float*)d_in[3];
  const float* b_ioux = (const float*)d_in[4];
  const float* W_iouh = (const float*)d_in[5];
  const float* b_iouh = (const float*)d_in[6];
  const float* W_fx   = (const float*)d_in[7];
  const float* b_fx   = (const float*)d_in[8];
  const float* W_Uh   = (const float*)d_in[9];
  const float* b_Uh   = (const float*)d_in[10];
  float* out = (float*)d_out;

  char* ws = (char*)d_ws;
  _Float16* xh = (_Float16*)ws;   ws += (size_t)MROWS * KDIM * 2;      // 33.5 MB
  _Float16* wbig = (_Float16*)ws; ws += (size_t)NOUT * KDIM * 2;       // 3.1 MB
  float* biasN = (float*)ws;      ws += (size_t)NOUT * 4;              // 6 KB
  _Float16* wrec = (_Float16*)ws; ws += (size_t)(2*NHID*NHID + NHID*NHID) * 2; // 1.5 MB
  float* proj = (float*)ws;       ws += (size_t)MROWS * NOUT * 4;      // 100.7 MB

  k_convert_x<<<2048, 256, 0, stream>>>(inputs, sememe, xh);
  k_convert_w<<<(NOUT * KDIM / 4) / 256, 256, 0, stream>>>(W_ioux, W_fx, b_ioux, b_fx, wbig, biasN);
  k_convert_wrec<<<(3 * NHID * NHID / 4) / 256, 256, 0, stream>>>(W_iouh, W_Uh, wrec);
  gemm_bt<<<(MROWS / 128) * (NOUT / 128), 256, 0, stream>>>(xh, wbig, biasN, proj, MROWS, NOUT, KDIM);
  recur<<<BATCH, 1024, 0, stream>>>(wrec, b_iouh, b_Uh, hx, proj, out);
}